// Round 6
// baseline (273.720 us; speedup 1.0000x reference)
//
#include <hip/hip_runtime.h>

#define TPB 256
#define LOG_NPB 9
#define NPB 512            // nodes per bucket (bucket = dst >> 9)
#define SPLIT 16           // blocks per bucket in accumulation passes
#define CHUNK 4096         // edges per bucketing block
#define EPT 16             // edges per thread in bucketing (CHUNK/TPB)
#define KMAX 256           // max buckets (N=100000 -> K=196)

// ===== ABLATION ROUND =====
// Identical to R4 (185us) except:
//  - k_pass1: +1 dead divergent gather per edge (asm-kept)  -> measures gather cost
//  - k_pass2: +2 net-zero LDS atomics per edge (+v then -v) -> measures atomic cost
// Results remain bit-correct (probe loads dead; probe atomics cancel).

__global__ void k_reset(int* __restrict__ gcur, int K) {
  int i = blockIdx.x * blockDim.x + threadIdx.x;
  if (i < K) gcur[i] = 0;
}

__global__ __launch_bounds__(TPB) void
k_bucket(const int* __restrict__ src, const int* __restrict__ dst,
         int E, int K, int cap,
         int* __restrict__ gcur, unsigned int* __restrict__ packed) {
  __shared__ unsigned int stage[CHUNK];               // 16 KB
  __shared__ unsigned char bkt[CHUNK];                // 4 KB
  __shared__ int hist[KMAX], start[KMAX], cur[KMAX], res[KMAX];
  __shared__ int sc[KMAX];

  const int t = threadIdx.x;
  const int e0 = blockIdx.x * CHUNK;
  const int e1 = min(e0 + CHUNK, E);
  const int cn = e1 - e0;

  for (int b = t; b < KMAX; b += TPB) hist[b] = 0;
  __syncthreads();

  unsigned int pk[EPT];
  unsigned int bb4[EPT / 4];
#pragma unroll
  for (int q = 0; q < EPT / 4; ++q) bb4[q] = 0xFFFFFFFFu;

  // phase 1: load (int4-coalesced), pack, histogram
#pragma unroll
  for (int q = 0; q < EPT / 4; ++q) {
    int base = e0 + 4 * t + q * 4 * TPB;
    if (base + 4 <= e1) {
      int4 dv = *reinterpret_cast<const int4*>(dst + base);
      int4 sv = *reinterpret_cast<const int4*>(src + base);
      int d[4] = {dv.x, dv.y, dv.z, dv.w};
      int s[4] = {sv.x, sv.y, sv.z, sv.w};
#pragma unroll
      for (int j = 0; j < 4; ++j) {
        int b = d[j] >> LOG_NPB;
        pk[4 * q + j] = ((unsigned)s[j] << LOG_NPB) | (unsigned)(d[j] & (NPB - 1));
        bb4[q] = (bb4[q] & ~(0xFFu << (8 * j))) | ((unsigned)b << (8 * j));
        atomicAdd(&hist[b], 1);
      }
    } else {
      for (int j = 0; j < 4; ++j) {
        int idx = base + j;
        if (idx < e1) {
          int d = dst[idx], s = src[idx];
          int b = d >> LOG_NPB;
          pk[4 * q + j] = ((unsigned)s << LOG_NPB) | (unsigned)(d & (NPB - 1));
          bb4[q] = (bb4[q] & ~(0xFFu << (8 * j))) | ((unsigned)b << (8 * j));
          atomicAdd(&hist[b], 1);
        }
      }
    }
  }
  __syncthreads();

  // phase 2: exclusive scan over KMAX bins (Hillis-Steele, TPB==KMAX)
  int hv = hist[t];
  sc[t] = hv;
  __syncthreads();
#pragma unroll
  for (int off = 1; off < KMAX; off <<= 1) {
    int u = (t >= off) ? sc[t - off] : 0;
    __syncthreads();
    sc[t] += u;
    __syncthreads();
  }
  start[t] = sc[t] - hv;
  cur[t] = sc[t] - hv;
  res[t] = (t < K && hv > 0) ? atomicAdd(&gcur[t], hv) : 0;
  __syncthreads();

  // phase 3: scatter into LDS sorted by bucket, remember bucket per slot
#pragma unroll
  for (int k = 0; k < EPT; ++k) {
    int b = (bb4[k >> 2] >> (8 * (k & 3))) & 255;
    if (b != 255) {
      int p = atomicAdd(&cur[b], 1);
      stage[p] = pk[k];
      bkt[p] = (unsigned char)b;
    }
  }
  __syncthreads();

  // phase 4: linear copy-out — all threads active, coalesced per-bucket runs
  for (int i = t; i < cn; i += TPB) {
    int b = bkt[i];
    int gp = res[b] + i - start[b];
    if (gp < cap) packed[(size_t)b * cap + gp] = stage[i];
  }
}

__device__ __forceinline__ void slice_range(int cnt, int s, int& off0, int& off1) {
  off0 = (int)(((long long)cnt * s) / SPLIT) & ~3;
  off1 = (s == SPLIT - 1) ? cnt : (int)(((long long)cnt * (s + 1)) / SPLIT) & ~3;
}

__global__ __launch_bounds__(TPB) void
k_deg(const unsigned int* __restrict__ packed, const int* __restrict__ gcur,
      int cap, int* __restrict__ pdeg, int Npad) {
  int b = blockIdx.x / SPLIT, s = blockIdx.x % SPLIT;
  __shared__ int bins[NPB];
  for (int i = threadIdx.x; i < NPB; i += TPB) bins[i] = 0;
  __syncthreads();
  int cnt = min(gcur[b], cap);
  int off0, off1; slice_range(cnt, s, off0, off1);
  const unsigned int* base = packed + (size_t)b * cap;
  int len = off1 - off0;
  int nfull = len >> 3;
  for (int g = threadIdx.x; g < nfull; g += TPB) {
    int e = off0 + (g << 3);
    uint4 pa = *reinterpret_cast<const uint4*>(base + e);
    uint4 pb = *reinterpret_cast<const uint4*>(base + e + 4);
    atomicAdd(&bins[pa.x & (NPB - 1)], 1);
    atomicAdd(&bins[pa.y & (NPB - 1)], 1);
    atomicAdd(&bins[pa.z & (NPB - 1)], 1);
    atomicAdd(&bins[pa.w & (NPB - 1)], 1);
    atomicAdd(&bins[pb.x & (NPB - 1)], 1);
    atomicAdd(&bins[pb.y & (NPB - 1)], 1);
    atomicAdd(&bins[pb.z & (NPB - 1)], 1);
    atomicAdd(&bins[pb.w & (NPB - 1)], 1);
  }
  for (int e = off0 + (nfull << 3) + threadIdx.x; e < off1; e += TPB)
    atomicAdd(&bins[base[e] & (NPB - 1)], 1);
  __syncthreads();
  int nb = b << LOG_NPB;
  for (int i = threadIdx.x; i < NPB; i += TPB)
    pdeg[s * Npad + nb + i] = bins[i];
}

__global__ void k_dinv(const int* __restrict__ pdeg, const float* __restrict__ x,
                       float* __restrict__ dinv, float* __restrict__ xd,
                       int N, int Npad) {
  int i = blockIdx.x * TPB + threadIdx.x;
  if (i >= N) return;
  int d = 1;  // self-loop
#pragma unroll
  for (int s = 0; s < SPLIT; ++s) d += pdeg[s * Npad + i];
  float di = rsqrtf((float)d);
  dinv[i] = di;
  xd[i] = x[i] * di;
}

// PROBE: one extra dead divergent gather per edge (distinct cache line, asm-kept)
#define PROBE_GATHER(idx)                                  \
  {                                                        \
    float _pv = xd[(idx) ^ 8191];                          \
    asm volatile("" ::"v"(_pv));                           \
  }

__global__ __launch_bounds__(TPB) void
k_pass1(const unsigned int* __restrict__ packed, const int* __restrict__ gcur,
        int cap, const float* __restrict__ xd, float* __restrict__ pt1, int Npad) {
  int b = blockIdx.x / SPLIT, s = blockIdx.x % SPLIT;
  __shared__ float bins[NPB];
  for (int i = threadIdx.x; i < NPB; i += TPB) bins[i] = 0.f;
  __syncthreads();
  int cnt = min(gcur[b], cap);
  int off0, off1; slice_range(cnt, s, off0, off1);
  const unsigned int* base = packed + (size_t)b * cap;
  int len = off1 - off0;
  int nfull = len >> 3;
  for (int g = threadIdx.x; g < nfull; g += TPB) {
    int e = off0 + (g << 3);
    uint4 pa = *reinterpret_cast<const uint4*>(base + e);
    uint4 pb = *reinterpret_cast<const uint4*>(base + e + 4);
    float v0 = xd[pa.x >> LOG_NPB];
    float v1 = xd[pa.y >> LOG_NPB];
    float v2 = xd[pa.z >> LOG_NPB];
    float v3 = xd[pa.w >> LOG_NPB];
    float v4 = xd[pb.x >> LOG_NPB];
    float v5 = xd[pb.y >> LOG_NPB];
    float v6 = xd[pb.z >> LOG_NPB];
    float v7 = xd[pb.w >> LOG_NPB];
    PROBE_GATHER(pa.x >> LOG_NPB);
    PROBE_GATHER(pa.y >> LOG_NPB);
    PROBE_GATHER(pa.z >> LOG_NPB);
    PROBE_GATHER(pa.w >> LOG_NPB);
    PROBE_GATHER(pb.x >> LOG_NPB);
    PROBE_GATHER(pb.y >> LOG_NPB);
    PROBE_GATHER(pb.z >> LOG_NPB);
    PROBE_GATHER(pb.w >> LOG_NPB);
    atomicAdd(&bins[pa.x & (NPB - 1)], v0);
    atomicAdd(&bins[pa.y & (NPB - 1)], v1);
    atomicAdd(&bins[pa.z & (NPB - 1)], v2);
    atomicAdd(&bins[pa.w & (NPB - 1)], v3);
    atomicAdd(&bins[pb.x & (NPB - 1)], v4);
    atomicAdd(&bins[pb.y & (NPB - 1)], v5);
    atomicAdd(&bins[pb.z & (NPB - 1)], v6);
    atomicAdd(&bins[pb.w & (NPB - 1)], v7);
  }
  for (int e = off0 + (nfull << 3) + threadIdx.x; e < off1; e += TPB) {
    unsigned int p = base[e];
    atomicAdd(&bins[p & (NPB - 1)], xd[p >> LOG_NPB]);
  }
  __syncthreads();
  int nb = b << LOG_NPB;
  for (int i = threadIdx.x; i < NPB; i += TPB)
    pt1[s * Npad + nb + i] = bins[i];
}

__global__ void k_node(const float* __restrict__ pt1, const float* __restrict__ xd,
                       const float* __restrict__ dinv,
                       const float* __restrict__ W1, const float* __restrict__ b1,
                       const float* __restrict__ W2,
                       float* __restrict__ gd, int N, int Npad) {
  int i = blockIdx.x * TPB + threadIdx.x;
  if (i >= N) return;
  float tv = 0.f;
#pragma unroll
  for (int s = 0; s < SPLIT; ++s) tv += pt1[s * Npad + i];
  float di = dinv[i];
  float sv = di * (tv + xd[i]);
  float g0 = 0.f, g1 = 0.f;
#pragma unroll
  for (int j = 0; j < 16; ++j) {
    float h = fmaxf(fmaf(sv, W1[j], b1[j]), 0.f);
    g0 = fmaf(h, W2[2 * j], g0);
    g1 = fmaf(h, W2[2 * j + 1], g1);
  }
  float2 o;
  o.x = g0 * di;
  o.y = g1 * di;
  *reinterpret_cast<float2*>(gd + 2 * i) = o;
}

// PROBE: net-zero extra atomic pair (+v then -v) — result unchanged
#define PROBE_ATOMIC(l, v)                                 \
  {                                                        \
    atomicAdd(&binx[(l)], (v));                            \
    atomicAdd(&binx[(l)], -(v));                           \
  }

__global__ __launch_bounds__(TPB) void
k_pass2(const unsigned int* __restrict__ packed, const int* __restrict__ gcur,
        int cap, const float* __restrict__ gd, float* __restrict__ pt2, int Npad) {
  int b = blockIdx.x / SPLIT, s = blockIdx.x % SPLIT;
  __shared__ float binx[NPB];
  __shared__ float biny[NPB];
  for (int i = threadIdx.x; i < NPB; i += TPB) { binx[i] = 0.f; biny[i] = 0.f; }
  __syncthreads();
  int cnt = min(gcur[b], cap);
  int off0, off1; slice_range(cnt, s, off0, off1);
  const unsigned int* base = packed + (size_t)b * cap;
  int len = off1 - off0;
  int nfull = len >> 3;
  for (int g = threadIdx.x; g < nfull; g += TPB) {
    int e = off0 + (g << 3);
    uint4 pa = *reinterpret_cast<const uint4*>(base + e);
    uint4 pb = *reinterpret_cast<const uint4*>(base + e + 4);
    float2 g0 = *reinterpret_cast<const float2*>(gd + 2 * (size_t)(pa.x >> LOG_NPB));
    float2 g1 = *reinterpret_cast<const float2*>(gd + 2 * (size_t)(pa.y >> LOG_NPB));
    float2 g2 = *reinterpret_cast<const float2*>(gd + 2 * (size_t)(pa.z >> LOG_NPB));
    float2 g3 = *reinterpret_cast<const float2*>(gd + 2 * (size_t)(pa.w >> LOG_NPB));
    float2 g4 = *reinterpret_cast<const float2*>(gd + 2 * (size_t)(pb.x >> LOG_NPB));
    float2 g5 = *reinterpret_cast<const float2*>(gd + 2 * (size_t)(pb.y >> LOG_NPB));
    float2 g6 = *reinterpret_cast<const float2*>(gd + 2 * (size_t)(pb.z >> LOG_NPB));
    float2 g7 = *reinterpret_cast<const float2*>(gd + 2 * (size_t)(pb.w >> LOG_NPB));
    atomicAdd(&binx[pa.x & (NPB - 1)], g0.x);
    atomicAdd(&biny[pa.x & (NPB - 1)], g0.y);
    atomicAdd(&binx[pa.y & (NPB - 1)], g1.x);
    atomicAdd(&biny[pa.y & (NPB - 1)], g1.y);
    atomicAdd(&binx[pa.z & (NPB - 1)], g2.x);
    atomicAdd(&biny[pa.z & (NPB - 1)], g2.y);
    atomicAdd(&binx[pa.w & (NPB - 1)], g3.x);
    atomicAdd(&biny[pa.w & (NPB - 1)], g3.y);
    atomicAdd(&binx[pb.x & (NPB - 1)], g4.x);
    atomicAdd(&biny[pb.x & (NPB - 1)], g4.y);
    atomicAdd(&binx[pb.y & (NPB - 1)], g5.x);
    atomicAdd(&biny[pb.y & (NPB - 1)], g5.y);
    atomicAdd(&binx[pb.z & (NPB - 1)], g6.x);
    atomicAdd(&biny[pb.z & (NPB - 1)], g6.y);
    atomicAdd(&binx[pb.w & (NPB - 1)], g7.x);
    atomicAdd(&biny[pb.w & (NPB - 1)], g7.y);
    PROBE_ATOMIC(pa.x & (NPB - 1), g0.x);
    PROBE_ATOMIC(pa.y & (NPB - 1), g1.x);
    PROBE_ATOMIC(pa.z & (NPB - 1), g2.x);
    PROBE_ATOMIC(pa.w & (NPB - 1), g3.x);
    PROBE_ATOMIC(pb.x & (NPB - 1), g4.x);
    PROBE_ATOMIC(pb.y & (NPB - 1), g5.x);
    PROBE_ATOMIC(pb.z & (NPB - 1), g6.x);
    PROBE_ATOMIC(pb.w & (NPB - 1), g7.x);
  }
  for (int e = off0 + (nfull << 3) + threadIdx.x; e < off1; e += TPB) {
    unsigned int p = base[e];
    float2 g = *reinterpret_cast<const float2*>(gd + 2 * (size_t)(p >> LOG_NPB));
    atomicAdd(&binx[p & (NPB - 1)], g.x);
    atomicAdd(&biny[p & (NPB - 1)], g.y);
  }
  __syncthreads();
  int nb = b << LOG_NPB;
  for (int i = threadIdx.x; i < NPB; i += TPB) {
    float2 o;
    o.x = binx[i];
    o.y = biny[i];
    *reinterpret_cast<float2*>(pt2 + (size_t)s * 2 * Npad + 2 * (nb + i)) = o;
  }
}

__global__ void k_final(const float* __restrict__ pt2, const float* __restrict__ gd,
                        const float* __restrict__ dinv, const float* __restrict__ b2,
                        float* __restrict__ out, int N, int Npad) {
  int i = blockIdx.x * TPB + threadIdx.x;
  if (i >= N) return;
  float t0 = 0.f, t1 = 0.f;
#pragma unroll
  for (int s = 0; s < SPLIT; ++s) {
    float2 p = *reinterpret_cast<const float2*>(pt2 + (size_t)s * 2 * Npad + 2 * i);
    t0 += p.x;
    t1 += p.y;
  }
  float di = dinv[i];
  float o0 = di * (t0 + gd[2 * i]) + b2[0];
  float o1 = di * (t1 + gd[2 * i + 1]) + b2[1];
  float m = fmaxf(o0, o1);
  float l = m + logf(expf(o0 - m) + expf(o1 - m));
  out[2 * i] = o0 - l;
  out[2 * i + 1] = o1 - l;
}

extern "C" void kernel_launch(void* const* d_in, const int* in_sizes, int n_in,
                              void* d_out, int out_size, void* d_ws, size_t ws_size,
                              hipStream_t stream) {
  const float* x  = (const float*)d_in[0];
  const int*   ei = (const int*)d_in[1];
  const float* W1 = (const float*)d_in[2];
  const float* b1 = (const float*)d_in[3];
  const float* W2 = (const float*)d_in[4];
  const float* b2 = (const float*)d_in[5];

  const int N = in_sizes[0];      // x is [N,1]
  const int E = in_sizes[1] / 2;  // edge_index is [2,E]
  const int* src = ei;
  const int* dst = ei + E;

  const int K = (N + NPB - 1) >> LOG_NPB;   // 196
  const int Npad = K << LOG_NPB;            // 100352
  int mean = (int)(((long long)E * NPB) / N);
  int cap = mean + mean / 16 + 512;         // slack >> binomial std
  cap = (cap + 3) & ~3;

  char* ws = (char*)d_ws;
  auto align256 = [&](size_t n) { char* p = ws; ws += (n + 255) & ~(size_t)255; return p; };

  int*          gcur   = (int*)align256((size_t)K * 4);
  unsigned int* packed = (unsigned int*)align256((size_t)K * cap * 4);
  float*        dinv   = (float*)align256((size_t)N * 4);
  float*        xd     = (float*)align256((size_t)N * 4);
  float*        gd     = (float*)align256((size_t)N * 8);
  // shared region R: pdeg / pt1 / pt2 (sequentially dead -> alias)
  float*        R      = (float*)align256((size_t)SPLIT * 2 * Npad * 4);
  int*          pdeg   = (int*)R;
  float*        pt1    = R;
  float*        pt2    = R;

  float* out = (float*)d_out;

  int nb_node   = (N + TPB - 1) / TPB;
  int nb_bucket = (E + CHUNK - 1) / CHUNK;
  int nb_acc    = K * SPLIT;

  k_reset <<<(K + TPB - 1) / TPB, TPB, 0, stream>>>(gcur, K);
  k_bucket<<<nb_bucket, TPB, 0, stream>>>(src, dst, E, K, cap, gcur, packed);
  k_deg   <<<nb_acc, TPB, 0, stream>>>(packed, gcur, cap, pdeg, Npad);
  k_dinv  <<<nb_node, TPB, 0, stream>>>(pdeg, x, dinv, xd, N, Npad);
  k_pass1 <<<nb_acc, TPB, 0, stream>>>(packed, gcur, cap, xd, pt1, Npad);
  k_node  <<<nb_node, TPB, 0, stream>>>(pt1, xd, dinv, W1, b1, W2, gd, N, Npad);
  k_pass2 <<<nb_acc, TPB, 0, stream>>>(packed, gcur, cap, gd, pt2, Npad);
  k_final <<<nb_node, TPB, 0, stream>>>(pt2, gd, dinv, b2, out, N, Npad);
}

// Round 7
// 153.601 us; speedup vs baseline: 1.7820x; 1.7820x over previous
//
#include <hip/hip_runtime.h>
#include <hip/hip_fp16.h>

#define TPB 256
#define LOG_NPB 9
#define NPB 512            // nodes per bucket (bucket = dst >> 9)
#define SPLIT 16           // blocks per bucket in accumulation passes
#define CHUNK 4096         // edges per bucketing block
#define EPT 16             // edges per thread in bucketing (CHUNK/TPB)
#define KMAX 256           // max buckets (N=100000 -> K=196)

// GCN collapse (in-dim=1, out-dim=2):
//   deg[n] = 1 + #incoming; dinv = deg^-1/2; xd = x*dinv
//   t1[n] = sum_{e:dst=n} xd[src];  s = dinv*(t1+xd)
//   g[n][k] = sum_j relu(s*W1[j]+b1[j])*W2[j][k];  gd = g*dinv (packed f16x2)
//   t2[n][k] = sum_{e:dst=n} gd[src][k]   <- ONE ds_pk_add_f16 per edge
//   o = dinv*(t2+gd) + b2;  out = log_softmax(o)
// R6 ablation: LDS-atomic count is the cost (35us per atomic/edge pass);
// pass2 drops 2 f32 atomics -> 1 pk_f16 atomic per edge.

__device__ __forceinline__ void lds_pk_add_f16(unsigned* addr, unsigned val) {
  // ds_pk_add_f16: packed half2 atomic add to LDS. Generic LDS pointer's low
  // 32 bits are the DS byte offset on AMDGCN (aperture-based), m0 preset.
  asm volatile("ds_pk_add_f16 %0, %1"
               :: "v"((unsigned)(unsigned long long)addr), "v"(val)
               : "memory");
}

__global__ void k_reset(int* __restrict__ gcur, int K) {
  int i = blockIdx.x * blockDim.x + threadIdx.x;
  if (i < K) gcur[i] = 0;
}

__global__ __launch_bounds__(TPB) void
k_bucket(const int* __restrict__ src, const int* __restrict__ dst,
         int E, int K, int cap,
         int* __restrict__ gcur, unsigned int* __restrict__ packed) {
  __shared__ unsigned int stage[CHUNK];               // 16 KB
  __shared__ unsigned char bkt[CHUNK];                // 4 KB
  __shared__ int hist[KMAX], start[KMAX], cur[KMAX], res[KMAX];
  __shared__ int sc[KMAX];

  const int t = threadIdx.x;
  const int e0 = blockIdx.x * CHUNK;
  const int e1 = min(e0 + CHUNK, E);
  const int cn = e1 - e0;

  for (int b = t; b < KMAX; b += TPB) hist[b] = 0;
  __syncthreads();

  unsigned int pk[EPT];
  unsigned int bb4[EPT / 4];
#pragma unroll
  for (int q = 0; q < EPT / 4; ++q) bb4[q] = 0xFFFFFFFFu;

  // phase 1: load (int4-coalesced), pack, histogram
#pragma unroll
  for (int q = 0; q < EPT / 4; ++q) {
    int base = e0 + 4 * t + q * 4 * TPB;
    if (base + 4 <= e1) {
      int4 dv = *reinterpret_cast<const int4*>(dst + base);
      int4 sv = *reinterpret_cast<const int4*>(src + base);
      int d[4] = {dv.x, dv.y, dv.z, dv.w};
      int s[4] = {sv.x, sv.y, sv.z, sv.w};
#pragma unroll
      for (int j = 0; j < 4; ++j) {
        int b = d[j] >> LOG_NPB;
        pk[4 * q + j] = ((unsigned)s[j] << LOG_NPB) | (unsigned)(d[j] & (NPB - 1));
        bb4[q] = (bb4[q] & ~(0xFFu << (8 * j))) | ((unsigned)b << (8 * j));
        atomicAdd(&hist[b], 1);
      }
    } else {
      for (int j = 0; j < 4; ++j) {
        int idx = base + j;
        if (idx < e1) {
          int d = dst[idx], s = src[idx];
          int b = d >> LOG_NPB;
          pk[4 * q + j] = ((unsigned)s << LOG_NPB) | (unsigned)(d & (NPB - 1));
          bb4[q] = (bb4[q] & ~(0xFFu << (8 * j))) | ((unsigned)b << (8 * j));
          atomicAdd(&hist[b], 1);
        }
      }
    }
  }
  __syncthreads();

  // phase 2: exclusive scan over KMAX bins (Hillis-Steele, TPB==KMAX)
  int hv = hist[t];
  sc[t] = hv;
  __syncthreads();
#pragma unroll
  for (int off = 1; off < KMAX; off <<= 1) {
    int u = (t >= off) ? sc[t - off] : 0;
    __syncthreads();
    sc[t] += u;
    __syncthreads();
  }
  start[t] = sc[t] - hv;
  cur[t] = sc[t] - hv;
  res[t] = (t < K && hv > 0) ? atomicAdd(&gcur[t], hv) : 0;
  __syncthreads();

  // phase 3: scatter into LDS sorted by bucket, remember bucket per slot
#pragma unroll
  for (int k = 0; k < EPT; ++k) {
    int b = (bb4[k >> 2] >> (8 * (k & 3))) & 255;
    if (b != 255) {
      int p = atomicAdd(&cur[b], 1);
      stage[p] = pk[k];
      bkt[p] = (unsigned char)b;
    }
  }
  __syncthreads();

  // phase 4: linear copy-out — all threads active, coalesced per-bucket runs
  for (int i = t; i < cn; i += TPB) {
    int b = bkt[i];
    int gp = res[b] + i - start[b];
    if (gp < cap) packed[(size_t)b * cap + gp] = stage[i];
  }
}

__device__ __forceinline__ void slice_range(int cnt, int s, int& off0, int& off1) {
  off0 = (int)(((long long)cnt * s) / SPLIT) & ~3;
  off1 = (s == SPLIT - 1) ? cnt : (int)(((long long)cnt * (s + 1)) / SPLIT) & ~3;
}

__global__ __launch_bounds__(TPB) void
k_deg(const unsigned int* __restrict__ packed, const int* __restrict__ gcur,
      int cap, int* __restrict__ pdeg, int Npad) {
  int b = blockIdx.x / SPLIT, s = blockIdx.x % SPLIT;
  __shared__ int bins[NPB];
  for (int i = threadIdx.x; i < NPB; i += TPB) bins[i] = 0;
  __syncthreads();
  int cnt = min(gcur[b], cap);
  int off0, off1; slice_range(cnt, s, off0, off1);
  const unsigned int* base = packed + (size_t)b * cap;
  int len = off1 - off0;
  int nfull = len >> 3;
  for (int g = threadIdx.x; g < nfull; g += TPB) {
    int e = off0 + (g << 3);
    uint4 pa = *reinterpret_cast<const uint4*>(base + e);
    uint4 pb = *reinterpret_cast<const uint4*>(base + e + 4);
    atomicAdd(&bins[pa.x & (NPB - 1)], 1);
    atomicAdd(&bins[pa.y & (NPB - 1)], 1);
    atomicAdd(&bins[pa.z & (NPB - 1)], 1);
    atomicAdd(&bins[pa.w & (NPB - 1)], 1);
    atomicAdd(&bins[pb.x & (NPB - 1)], 1);
    atomicAdd(&bins[pb.y & (NPB - 1)], 1);
    atomicAdd(&bins[pb.z & (NPB - 1)], 1);
    atomicAdd(&bins[pb.w & (NPB - 1)], 1);
  }
  for (int e = off0 + (nfull << 3) + threadIdx.x; e < off1; e += TPB)
    atomicAdd(&bins[base[e] & (NPB - 1)], 1);
  __syncthreads();
  int nb = b << LOG_NPB;
  for (int i = threadIdx.x; i < NPB; i += TPB)
    pdeg[s * Npad + nb + i] = bins[i];
}

__global__ void k_dinv(const int* __restrict__ pdeg, const float* __restrict__ x,
                       float* __restrict__ dinv, float* __restrict__ xd,
                       int N, int Npad) {
  int i = blockIdx.x * TPB + threadIdx.x;
  if (i >= N) return;
  int d = 1;  // self-loop
#pragma unroll
  for (int s = 0; s < SPLIT; ++s) d += pdeg[s * Npad + i];
  float di = rsqrtf((float)d);
  dinv[i] = di;
  xd[i] = x[i] * di;
}

__global__ __launch_bounds__(TPB) void
k_pass1(const unsigned int* __restrict__ packed, const int* __restrict__ gcur,
        int cap, const float* __restrict__ xd, float* __restrict__ pt1, int Npad) {
  int b = blockIdx.x / SPLIT, s = blockIdx.x % SPLIT;
  __shared__ float bins[NPB];
  for (int i = threadIdx.x; i < NPB; i += TPB) bins[i] = 0.f;
  __syncthreads();
  int cnt = min(gcur[b], cap);
  int off0, off1; slice_range(cnt, s, off0, off1);
  const unsigned int* base = packed + (size_t)b * cap;
  int len = off1 - off0;
  int nfull = len >> 3;
  for (int g = threadIdx.x; g < nfull; g += TPB) {
    int e = off0 + (g << 3);
    uint4 pa = *reinterpret_cast<const uint4*>(base + e);
    uint4 pb = *reinterpret_cast<const uint4*>(base + e + 4);
    float v0 = xd[pa.x >> LOG_NPB];
    float v1 = xd[pa.y >> LOG_NPB];
    float v2 = xd[pa.z >> LOG_NPB];
    float v3 = xd[pa.w >> LOG_NPB];
    float v4 = xd[pb.x >> LOG_NPB];
    float v5 = xd[pb.y >> LOG_NPB];
    float v6 = xd[pb.z >> LOG_NPB];
    float v7 = xd[pb.w >> LOG_NPB];
    atomicAdd(&bins[pa.x & (NPB - 1)], v0);
    atomicAdd(&bins[pa.y & (NPB - 1)], v1);
    atomicAdd(&bins[pa.z & (NPB - 1)], v2);
    atomicAdd(&bins[pa.w & (NPB - 1)], v3);
    atomicAdd(&bins[pb.x & (NPB - 1)], v4);
    atomicAdd(&bins[pb.y & (NPB - 1)], v5);
    atomicAdd(&bins[pb.z & (NPB - 1)], v6);
    atomicAdd(&bins[pb.w & (NPB - 1)], v7);
  }
  for (int e = off0 + (nfull << 3) + threadIdx.x; e < off1; e += TPB) {
    unsigned int p = base[e];
    atomicAdd(&bins[p & (NPB - 1)], xd[p >> LOG_NPB]);
  }
  __syncthreads();
  int nb = b << LOG_NPB;
  for (int i = threadIdx.x; i < NPB; i += TPB)
    pt1[s * Npad + nb + i] = bins[i];
}

__global__ void k_node(const float* __restrict__ pt1, const float* __restrict__ xd,
                       const float* __restrict__ dinv,
                       const float* __restrict__ W1, const float* __restrict__ b1,
                       const float* __restrict__ W2,
                       unsigned* __restrict__ gdp, int N, int Npad) {
  int i = blockIdx.x * TPB + threadIdx.x;
  if (i >= N) return;
  float tv = 0.f;
#pragma unroll
  for (int s = 0; s < SPLIT; ++s) tv += pt1[s * Npad + i];
  float di = dinv[i];
  float sv = di * (tv + xd[i]);
  float g0 = 0.f, g1 = 0.f;
#pragma unroll
  for (int j = 0; j < 16; ++j) {
    float h = fmaxf(fmaf(sv, W1[j], b1[j]), 0.f);
    g0 = fmaf(h, W2[2 * j], g0);
    g1 = fmaf(h, W2[2 * j + 1], g1);
  }
  __half2 h2 = __floats2half2_rn(g0 * di, g1 * di);
  gdp[i] = *reinterpret_cast<unsigned*>(&h2);
}

__global__ __launch_bounds__(TPB) void
k_pass2(const unsigned int* __restrict__ packed, const int* __restrict__ gcur,
        int cap, const unsigned* __restrict__ gdp, float* __restrict__ pt2, int Npad) {
  int b = blockIdx.x / SPLIT, s = blockIdx.x % SPLIT;
  __shared__ unsigned bins[NPB];          // packed f16x2 accumulators
  for (int i = threadIdx.x; i < NPB; i += TPB) bins[i] = 0u;  // (+0,+0)
  __syncthreads();
  int cnt = min(gcur[b], cap);
  int off0, off1; slice_range(cnt, s, off0, off1);
  const unsigned int* base = packed + (size_t)b * cap;
  int len = off1 - off0;
  int nfull = len >> 3;
  for (int g = threadIdx.x; g < nfull; g += TPB) {
    int e = off0 + (g << 3);
    uint4 pa = *reinterpret_cast<const uint4*>(base + e);
    uint4 pb = *reinterpret_cast<const uint4*>(base + e + 4);
    unsigned v0 = gdp[pa.x >> LOG_NPB];
    unsigned v1 = gdp[pa.y >> LOG_NPB];
    unsigned v2 = gdp[pa.z >> LOG_NPB];
    unsigned v3 = gdp[pa.w >> LOG_NPB];
    unsigned v4 = gdp[pb.x >> LOG_NPB];
    unsigned v5 = gdp[pb.y >> LOG_NPB];
    unsigned v6 = gdp[pb.z >> LOG_NPB];
    unsigned v7 = gdp[pb.w >> LOG_NPB];
    lds_pk_add_f16(&bins[pa.x & (NPB - 1)], v0);
    lds_pk_add_f16(&bins[pa.y & (NPB - 1)], v1);
    lds_pk_add_f16(&bins[pa.z & (NPB - 1)], v2);
    lds_pk_add_f16(&bins[pa.w & (NPB - 1)], v3);
    lds_pk_add_f16(&bins[pb.x & (NPB - 1)], v4);
    lds_pk_add_f16(&bins[pb.y & (NPB - 1)], v5);
    lds_pk_add_f16(&bins[pb.z & (NPB - 1)], v6);
    lds_pk_add_f16(&bins[pb.w & (NPB - 1)], v7);
  }
  for (int e = off0 + (nfull << 3) + threadIdx.x; e < off1; e += TPB) {
    unsigned int p = base[e];
    lds_pk_add_f16(&bins[p & (NPB - 1)], gdp[p >> LOG_NPB]);
  }
  __syncthreads();
  int nb = b << LOG_NPB;
  for (int i = threadIdx.x; i < NPB; i += TPB) {
    __half2 h = *reinterpret_cast<__half2*>(&bins[i]);
    float2 o;
    o.x = __low2float(h);
    o.y = __high2float(h);
    *reinterpret_cast<float2*>(pt2 + (size_t)s * 2 * Npad + 2 * (nb + i)) = o;
  }
}

__global__ void k_final(const float* __restrict__ pt2, const unsigned* __restrict__ gdp,
                        const float* __restrict__ dinv, const float* __restrict__ b2,
                        float* __restrict__ out, int N, int Npad) {
  int i = blockIdx.x * TPB + threadIdx.x;
  if (i >= N) return;
  float t0 = 0.f, t1 = 0.f;
#pragma unroll
  for (int s = 0; s < SPLIT; ++s) {
    float2 p = *reinterpret_cast<const float2*>(pt2 + (size_t)s * 2 * Npad + 2 * i);
    t0 += p.x;
    t1 += p.y;
  }
  unsigned gp = gdp[i];
  __half2 h = *reinterpret_cast<__half2*>(&gp);
  float di = dinv[i];
  float o0 = di * (t0 + __low2float(h)) + b2[0];
  float o1 = di * (t1 + __high2float(h)) + b2[1];
  float m = fmaxf(o0, o1);
  float l = m + logf(expf(o0 - m) + expf(o1 - m));
  out[2 * i] = o0 - l;
  out[2 * i + 1] = o1 - l;
}

extern "C" void kernel_launch(void* const* d_in, const int* in_sizes, int n_in,
                              void* d_out, int out_size, void* d_ws, size_t ws_size,
                              hipStream_t stream) {
  const float* x  = (const float*)d_in[0];
  const int*   ei = (const int*)d_in[1];
  const float* W1 = (const float*)d_in[2];
  const float* b1 = (const float*)d_in[3];
  const float* W2 = (const float*)d_in[4];
  const float* b2 = (const float*)d_in[5];

  const int N = in_sizes[0];      // x is [N,1]
  const int E = in_sizes[1] / 2;  // edge_index is [2,E]
  const int* src = ei;
  const int* dst = ei + E;

  const int K = (N + NPB - 1) >> LOG_NPB;   // 196
  const int Npad = K << LOG_NPB;            // 100352
  int mean = (int)(((long long)E * NPB) / N);
  int cap = mean + mean / 16 + 512;         // slack >> binomial std
  cap = (cap + 3) & ~3;

  char* ws = (char*)d_ws;
  auto align256 = [&](size_t n) { char* p = ws; ws += (n + 255) & ~(size_t)255; return p; };

  int*          gcur   = (int*)align256((size_t)K * 4);
  unsigned int* packed = (unsigned int*)align256((size_t)K * cap * 4);
  float*        dinv   = (float*)align256((size_t)N * 4);
  float*        xd     = (float*)align256((size_t)N * 4);
  unsigned*     gdp    = (unsigned*)align256((size_t)N * 4);
  // shared region R: pdeg / pt1 / pt2 (sequentially dead -> alias)
  float*        R      = (float*)align256((size_t)SPLIT * 2 * Npad * 4);
  int*          pdeg   = (int*)R;
  float*        pt1    = R;
  float*        pt2    = R;

  float* out = (float*)d_out;

  int nb_node   = (N + TPB - 1) / TPB;
  int nb_bucket = (E + CHUNK - 1) / CHUNK;
  int nb_acc    = K * SPLIT;

  k_reset <<<(K + TPB - 1) / TPB, TPB, 0, stream>>>(gcur, K);
  k_bucket<<<nb_bucket, TPB, 0, stream>>>(src, dst, E, K, cap, gcur, packed);
  k_deg   <<<nb_acc, TPB, 0, stream>>>(packed, gcur, cap, pdeg, Npad);
  k_dinv  <<<nb_node, TPB, 0, stream>>>(pdeg, x, dinv, xd, N, Npad);
  k_pass1 <<<nb_acc, TPB, 0, stream>>>(packed, gcur, cap, xd, pt1, Npad);
  k_node  <<<nb_node, TPB, 0, stream>>>(pt1, xd, dinv, W1, b1, W2, gdp, N, Npad);
  k_pass2 <<<nb_acc, TPB, 0, stream>>>(packed, gcur, cap, gdp, pt2, Npad);
  k_final <<<nb_node, TPB, 0, stream>>>(pt2, gdp, dinv, b2, out, N, Npad);
}

// Round 8
// 147.601 us; speedup vs baseline: 1.8545x; 1.0406x over previous
//
#include <hip/hip_runtime.h>
#include <hip/hip_fp16.h>

#define TPB 256
#define LOG_NPB 9
#define NPB 512            // nodes per bucket (bucket = dst >> 9)
#define SPLIT 16           // blocks per bucket in accumulation passes
#define CHUNK 4096         // edges per bucketing block
#define RCAP 44            // per-(chunk,bucket) LDS region capacity (λ=21, +5σ, overflow handled)

// GCN collapse (in-dim=1, out-dim=2):
//   deg[n] = 1 + #incoming; dinv = deg^-1/2; xd = x*dinv
//   t1[n] = sum_{e:dst=n} xd[src];  s = dinv*(t1+xd)
//   g[n][k] = sum_j relu(s*W1[j]+b1[j])*W2[j][k];  gd = g*dinv (packed f16x2)
//   t2[n][k] = sum_{e:dst=n} gd[src][k]   (ONE ds_pk_add_f16 per edge)
//   o = dinv*(t2+gd) + b2;  out = log_softmax(o)
// Cost model (R6 ablation): ~35us per LDS-atomic-per-edge pass. Ledger:
// bucket(1 atomic, region scatter) + deg(1) + pass1(1) + pass2(1 pk).

__device__ __forceinline__ void lds_pk_add_f16(unsigned* addr, unsigned val) {
  asm volatile("ds_pk_add_f16 %0, %1"
               :: "v"((unsigned)(unsigned long long)addr), "v"(val)
               : "memory");
}

__global__ void k_reset(int* __restrict__ gcur, int K) {
  int i = blockIdx.x * blockDim.x + threadIdx.x;
  if (i < K) gcur[i] = 0;
}

// Single-atomic region-scatter bucketing: cur[b] cursor -> stage[b*RCAP+p];
// overflow edges self-reserve directly in gcur (rare); bulk reservation after.
__global__ __launch_bounds__(TPB) void
k_bucket(const int* __restrict__ src, const int* __restrict__ dst,
         int E, int K, int capG,
         int* __restrict__ gcur, unsigned int* __restrict__ packed) {
  extern __shared__ unsigned smem[];
  unsigned* stage = smem;                              // K*RCAP
  int* cur = (int*)(smem + (size_t)K * RCAP);          // K
  int* res = cur + K;                                  // K

  const int t = threadIdx.x;
  const int e0 = blockIdx.x * CHUNK;
  const int e1 = min(e0 + CHUNK, E);

  for (int b = t; b < K; b += TPB) cur[b] = 0;
  __syncthreads();

  for (int base = e0 + 4 * t; base < e1; base += 4 * TPB) {
    if (base + 4 <= e1) {
      int4 dv = *reinterpret_cast<const int4*>(dst + base);
      int4 sv = *reinterpret_cast<const int4*>(src + base);
      int d[4] = {dv.x, dv.y, dv.z, dv.w};
      int s[4] = {sv.x, sv.y, sv.z, sv.w};
#pragma unroll
      for (int j = 0; j < 4; ++j) {
        int b = d[j] >> LOG_NPB;
        unsigned pk = ((unsigned)s[j] << LOG_NPB) | (unsigned)(d[j] & (NPB - 1));
        int p = atomicAdd(&cur[b], 1);
        if (p < RCAP) {
          stage[b * RCAP + p] = pk;
        } else {                       // rare overflow: direct global slot
          int gp = atomicAdd(&gcur[b], 1);
          if (gp < capG) packed[(size_t)b * capG + gp] = pk;
        }
      }
    } else {
      for (int j = 0; j < 4; ++j) {
        int idx = base + j;
        if (idx < e1) {
          int d = dst[idx], s = src[idx];
          int b = d >> LOG_NPB;
          unsigned pk = ((unsigned)s << LOG_NPB) | (unsigned)(d & (NPB - 1));
          int p = atomicAdd(&cur[b], 1);
          if (p < RCAP) {
            stage[b * RCAP + p] = pk;
          } else {
            int gp = atomicAdd(&gcur[b], 1);
            if (gp < capG) packed[(size_t)b * capG + gp] = pk;
          }
        }
      }
    }
  }
  __syncthreads();

  if (t < K) {
    int c = min(cur[t], RCAP);
    res[t] = (c > 0) ? atomicAdd(&gcur[t], c) : 0;
  }
  __syncthreads();

  // linear copy-out over regions: coalesced per-bucket runs
  const int tot = K * RCAP;
  for (int i = t; i < tot; i += TPB) {
    int b = i / RCAP;
    int pos = i - b * RCAP;
    if (pos < min(cur[b], RCAP)) {
      int gp = res[b] + pos;
      if (gp < capG) packed[(size_t)b * capG + gp] = stage[i];
    }
  }
}

__device__ __forceinline__ void slice_range(int cnt, int s, int& off0, int& off1) {
  off0 = (int)(((long long)cnt * s) / SPLIT) & ~3;
  off1 = (s == SPLIT - 1) ? cnt : (int)(((long long)cnt * (s + 1)) / SPLIT) & ~3;
}

__global__ __launch_bounds__(TPB) void
k_deg(const unsigned int* __restrict__ packed, const int* __restrict__ gcur,
      int cap, int* __restrict__ pdeg, int Npad) {
  int b = blockIdx.x / SPLIT, s = blockIdx.x % SPLIT;
  __shared__ int bins[NPB];
  for (int i = threadIdx.x; i < NPB; i += TPB) bins[i] = 0;
  __syncthreads();
  int cnt = min(gcur[b], cap);
  int off0, off1; slice_range(cnt, s, off0, off1);
  const unsigned int* base = packed + (size_t)b * cap;
  int len = off1 - off0;
  int nfull = len >> 3;
  for (int g = threadIdx.x; g < nfull; g += TPB) {
    int e = off0 + (g << 3);
    uint4 pa = *reinterpret_cast<const uint4*>(base + e);
    uint4 pb = *reinterpret_cast<const uint4*>(base + e + 4);
    atomicAdd(&bins[pa.x & (NPB - 1)], 1);
    atomicAdd(&bins[pa.y & (NPB - 1)], 1);
    atomicAdd(&bins[pa.z & (NPB - 1)], 1);
    atomicAdd(&bins[pa.w & (NPB - 1)], 1);
    atomicAdd(&bins[pb.x & (NPB - 1)], 1);
    atomicAdd(&bins[pb.y & (NPB - 1)], 1);
    atomicAdd(&bins[pb.z & (NPB - 1)], 1);
    atomicAdd(&bins[pb.w & (NPB - 1)], 1);
  }
  for (int e = off0 + (nfull << 3) + threadIdx.x; e < off1; e += TPB)
    atomicAdd(&bins[base[e] & (NPB - 1)], 1);
  __syncthreads();
  int nb = b << LOG_NPB;
  for (int i = threadIdx.x; i < NPB; i += TPB)
    pdeg[s * Npad + nb + i] = bins[i];
}

__global__ void k_dinv(const int* __restrict__ pdeg, const float* __restrict__ x,
                       float* __restrict__ dinv, float* __restrict__ xd,
                       int N, int Npad) {
  int i = blockIdx.x * TPB + threadIdx.x;
  if (i >= N) return;
  int d = 1;  // self-loop
#pragma unroll
  for (int s = 0; s < SPLIT; ++s) d += pdeg[s * Npad + i];
  float di = rsqrtf((float)d);
  dinv[i] = di;
  xd[i] = x[i] * di;
}

__global__ __launch_bounds__(TPB) void
k_pass1(const unsigned int* __restrict__ packed, const int* __restrict__ gcur,
        int cap, const float* __restrict__ xd, float* __restrict__ pt1, int Npad) {
  int b = blockIdx.x / SPLIT, s = blockIdx.x % SPLIT;
  __shared__ float bins[NPB];
  for (int i = threadIdx.x; i < NPB; i += TPB) bins[i] = 0.f;
  __syncthreads();
  int cnt = min(gcur[b], cap);
  int off0, off1; slice_range(cnt, s, off0, off1);
  const unsigned int* base = packed + (size_t)b * cap;
  int len = off1 - off0;
  int nfull = len >> 3;
  for (int g = threadIdx.x; g < nfull; g += TPB) {
    int e = off0 + (g << 3);
    uint4 pa = *reinterpret_cast<const uint4*>(base + e);
    uint4 pb = *reinterpret_cast<const uint4*>(base + e + 4);
    float v0 = xd[pa.x >> LOG_NPB];
    float v1 = xd[pa.y >> LOG_NPB];
    float v2 = xd[pa.z >> LOG_NPB];
    float v3 = xd[pa.w >> LOG_NPB];
    float v4 = xd[pb.x >> LOG_NPB];
    float v5 = xd[pb.y >> LOG_NPB];
    float v6 = xd[pb.z >> LOG_NPB];
    float v7 = xd[pb.w >> LOG_NPB];
    atomicAdd(&bins[pa.x & (NPB - 1)], v0);
    atomicAdd(&bins[pa.y & (NPB - 1)], v1);
    atomicAdd(&bins[pa.z & (NPB - 1)], v2);
    atomicAdd(&bins[pa.w & (NPB - 1)], v3);
    atomicAdd(&bins[pb.x & (NPB - 1)], v4);
    atomicAdd(&bins[pb.y & (NPB - 1)], v5);
    atomicAdd(&bins[pb.z & (NPB - 1)], v6);
    atomicAdd(&bins[pb.w & (NPB - 1)], v7);
  }
  for (int e = off0 + (nfull << 3) + threadIdx.x; e < off1; e += TPB) {
    unsigned int p = base[e];
    atomicAdd(&bins[p & (NPB - 1)], xd[p >> LOG_NPB]);
  }
  __syncthreads();
  int nb = b << LOG_NPB;
  for (int i = threadIdx.x; i < NPB; i += TPB)
    pt1[s * Npad + nb + i] = bins[i];
}

__global__ void k_node(const float* __restrict__ pt1, const float* __restrict__ xd,
                       const float* __restrict__ dinv,
                       const float* __restrict__ W1, const float* __restrict__ b1,
                       const float* __restrict__ W2,
                       unsigned* __restrict__ gdp, int N, int Npad) {
  int i = blockIdx.x * TPB + threadIdx.x;
  if (i >= N) return;
  float tv = 0.f;
#pragma unroll
  for (int s = 0; s < SPLIT; ++s) tv += pt1[s * Npad + i];
  float di = dinv[i];
  float sv = di * (tv + xd[i]);
  float g0 = 0.f, g1 = 0.f;
#pragma unroll
  for (int j = 0; j < 16; ++j) {
    float h = fmaxf(fmaf(sv, W1[j], b1[j]), 0.f);
    g0 = fmaf(h, W2[2 * j], g0);
    g1 = fmaf(h, W2[2 * j + 1], g1);
  }
  __half2 h2 = __floats2half2_rn(g0 * di, g1 * di);
  gdp[i] = *reinterpret_cast<unsigned*>(&h2);
}

__global__ __launch_bounds__(TPB) void
k_pass2(const unsigned int* __restrict__ packed, const int* __restrict__ gcur,
        int cap, const unsigned* __restrict__ gdp, float* __restrict__ pt2, int Npad) {
  int b = blockIdx.x / SPLIT, s = blockIdx.x % SPLIT;
  __shared__ unsigned bins[NPB];          // packed f16x2 accumulators
  for (int i = threadIdx.x; i < NPB; i += TPB) bins[i] = 0u;  // (+0,+0)
  __syncthreads();
  int cnt = min(gcur[b], cap);
  int off0, off1; slice_range(cnt, s, off0, off1);
  const unsigned int* base = packed + (size_t)b * cap;
  int len = off1 - off0;
  int nfull = len >> 3;
  for (int g = threadIdx.x; g < nfull; g += TPB) {
    int e = off0 + (g << 3);
    uint4 pa = *reinterpret_cast<const uint4*>(base + e);
    uint4 pb = *reinterpret_cast<const uint4*>(base + e + 4);
    unsigned v0 = gdp[pa.x >> LOG_NPB];
    unsigned v1 = gdp[pa.y >> LOG_NPB];
    unsigned v2 = gdp[pa.z >> LOG_NPB];
    unsigned v3 = gdp[pa.w >> LOG_NPB];
    unsigned v4 = gdp[pb.x >> LOG_NPB];
    unsigned v5 = gdp[pb.y >> LOG_NPB];
    unsigned v6 = gdp[pb.z >> LOG_NPB];
    unsigned v7 = gdp[pb.w >> LOG_NPB];
    lds_pk_add_f16(&bins[pa.x & (NPB - 1)], v0);
    lds_pk_add_f16(&bins[pa.y & (NPB - 1)], v1);
    lds_pk_add_f16(&bins[pa.z & (NPB - 1)], v2);
    lds_pk_add_f16(&bins[pa.w & (NPB - 1)], v3);
    lds_pk_add_f16(&bins[pb.x & (NPB - 1)], v4);
    lds_pk_add_f16(&bins[pb.y & (NPB - 1)], v5);
    lds_pk_add_f16(&bins[pb.z & (NPB - 1)], v6);
    lds_pk_add_f16(&bins[pb.w & (NPB - 1)], v7);
  }
  for (int e = off0 + (nfull << 3) + threadIdx.x; e < off1; e += TPB) {
    unsigned int p = base[e];
    lds_pk_add_f16(&bins[p & (NPB - 1)], gdp[p >> LOG_NPB]);
  }
  __syncthreads();
  int nb = b << LOG_NPB;
  for (int i = threadIdx.x; i < NPB; i += TPB) {
    __half2 h = *reinterpret_cast<__half2*>(&bins[i]);
    float2 o;
    o.x = __low2float(h);
    o.y = __high2float(h);
    *reinterpret_cast<float2*>(pt2 + (size_t)s * 2 * Npad + 2 * (nb + i)) = o;
  }
}

__global__ void k_final(const float* __restrict__ pt2, const unsigned* __restrict__ gdp,
                        const float* __restrict__ dinv, const float* __restrict__ b2,
                        float* __restrict__ out, int N, int Npad) {
  int i = blockIdx.x * TPB + threadIdx.x;
  if (i >= N) return;
  float t0 = 0.f, t1 = 0.f;
#pragma unroll
  for (int s = 0; s < SPLIT; ++s) {
    float2 p = *reinterpret_cast<const float2*>(pt2 + (size_t)s * 2 * Npad + 2 * i);
    t0 += p.x;
    t1 += p.y;
  }
  unsigned gp = gdp[i];
  __half2 h = *reinterpret_cast<__half2*>(&gp);
  float di = dinv[i];
  float o0 = di * (t0 + __low2float(h)) + b2[0];
  float o1 = di * (t1 + __high2float(h)) + b2[1];
  float m = fmaxf(o0, o1);
  float l = m + logf(expf(o0 - m) + expf(o1 - m));
  out[2 * i] = o0 - l;
  out[2 * i + 1] = o1 - l;
}

extern "C" void kernel_launch(void* const* d_in, const int* in_sizes, int n_in,
                              void* d_out, int out_size, void* d_ws, size_t ws_size,
                              hipStream_t stream) {
  const float* x  = (const float*)d_in[0];
  const int*   ei = (const int*)d_in[1];
  const float* W1 = (const float*)d_in[2];
  const float* b1 = (const float*)d_in[3];
  const float* W2 = (const float*)d_in[4];
  const float* b2 = (const float*)d_in[5];

  const int N = in_sizes[0];      // x is [N,1]
  const int E = in_sizes[1] / 2;  // edge_index is [2,E]
  const int* src = ei;
  const int* dst = ei + E;

  const int K = (N + NPB - 1) >> LOG_NPB;   // 196
  const int Npad = K << LOG_NPB;            // 100352
  int mean = (int)(((long long)E * NPB) / N);
  int cap = mean + mean / 16 + 512;         // slack >> binomial std
  cap = (cap + 3) & ~3;

  char* ws = (char*)d_ws;
  auto align256 = [&](size_t n) { char* p = ws; ws += (n + 255) & ~(size_t)255; return p; };

  int*          gcur   = (int*)align256((size_t)K * 4);
  unsigned int* packed = (unsigned int*)align256((size_t)K * cap * 4);
  float*        dinv   = (float*)align256((size_t)N * 4);
  float*        xd     = (float*)align256((size_t)N * 4);
  unsigned*     gdp    = (unsigned*)align256((size_t)N * 4);
  // shared region R: pdeg / pt1 / pt2 (sequentially dead -> alias)
  float*        R      = (float*)align256((size_t)SPLIT * 2 * Npad * 4);
  int*          pdeg   = (int*)R;
  float*        pt1    = R;
  float*        pt2    = R;

  float* out = (float*)d_out;

  int nb_node   = (N + TPB - 1) / TPB;
  int nb_bucket = (E + CHUNK - 1) / CHUNK;
  int nb_acc    = K * SPLIT;
  size_t sh_bucket = ((size_t)K * RCAP + 2 * (size_t)K) * 4;

  k_reset <<<(K + TPB - 1) / TPB, TPB, 0, stream>>>(gcur, K);
  k_bucket<<<nb_bucket, TPB, sh_bucket, stream>>>(src, dst, E, K, cap, gcur, packed);
  k_deg   <<<nb_acc, TPB, 0, stream>>>(packed, gcur, cap, pdeg, Npad);
  k_dinv  <<<nb_node, TPB, 0, stream>>>(pdeg, x, dinv, xd, N, Npad);
  k_pass1 <<<nb_acc, TPB, 0, stream>>>(packed, gcur, cap, xd, pt1, Npad);
  k_node  <<<nb_node, TPB, 0, stream>>>(pt1, xd, dinv, W1, b1, W2, gdp, N, Npad);
  k_pass2 <<<nb_acc, TPB, 0, stream>>>(packed, gcur, cap, gdp, pt2, Npad);
  k_final <<<nb_node, TPB, 0, stream>>>(pt2, gdp, dinv, b2, out, N, Npad);
}